// Round 5
// baseline (1292.434 us; speedup 1.0000x reference)
//
#include <hip/hip_runtime.h>
#include <hip/hip_bf16.h>

// Problem constants (fixed by setup_inputs):
//   B=1, T=16384 -> S=16384, C=1280, H=16, D=80, 3C=3840, block=16, nb=1024
// Inputs are FP32 (reference dtype; proven: R4 dtype-sniff == R3 fp32 path).
// Output d_out is FP32 (reference output dtype; bf16-write hypothesis falsified
// by R2-R4's bit-identical absmax 4.765625 = interleaved-readback signature).
#define S_TOK   16384
#define C_DIM   1280
#define C3_DIM  3840
#define H_DIM   16
#define D_DIM   80
#define BLK     16

using u16x8  = __attribute__((ext_vector_type(8))) unsigned short;
using bf16x8 = __attribute__((ext_vector_type(8))) __bf16;
using f32x4  = __attribute__((ext_vector_type(4))) float;

__device__ __forceinline__ unsigned short f2bf(float f) {
    return __bfloat16_as_ushort(__float2bfloat16(f));
}

// ---------------------------------------------------------------------------
// Tiled bf16 MFMA GEMM. A: fp32 (AF32) or bf16, converted during LDS staging.
// B: fp32, converted during staging. Optional A-row gather:
//   C[m][n] = sum_k A[gather(m)][k] * B[k][n]
// Output: fp32 (OUTF32) or bf16.
// 128x128 tile, BK=64, 256 threads = 4 waves (2x2), each wave 64x64 via
// 4x4 grid of 16x16x32 MFMAs. B transposed into LDS so both operand
// fragments are contiguous 16B ds_read_b128.
// ---------------------------------------------------------------------------
#define TM 128
#define TN 128
#define BK 64
#define LDST 72   // BK + 8 pad; row stride 144 B keeps 16B alignment

template<bool AF32, bool GATHER, bool OUTF32>
__global__ __launch_bounds__(256) void gemm_mfma(
    const void* __restrict__ Ap,      // [M][K] fp32 if AF32 else bf16
    const float* __restrict__ Bp,     // [K][N] fp32
    void* __restrict__ Cp,            // [M][N] fp32 if OUTF32 else bf16
    const int* __restrict__ row_idx,  // used iff GATHER
    int N, int K)
{
    __shared__ __align__(16) unsigned short As[TM][LDST];
    __shared__ __align__(16) unsigned short Bs[TN][LDST];  // transposed: Bs[n][k]

    const int m0   = blockIdx.x * TM;
    const int n0   = blockIdx.y * TN;
    const int tid  = threadIdx.x;
    const int lane = tid & 63;
    const int wave = tid >> 6;
    const int wm   = (wave >> 1) * 64;
    const int wn   = (wave & 1) * 64;
    const int lrow = lane & 15;
    const int quad = lane >> 4;

    f32x4 acc[4][4];
#pragma unroll
    for (int i = 0; i < 4; i++)
#pragma unroll
        for (int j = 0; j < 4; j++)
            acc[i][j] = (f32x4){0.f, 0.f, 0.f, 0.f};

    for (int kt = 0; kt < K; kt += BK) {
        // --- stage A: 128 rows x 64 k, 1024 chunks of 8 elems, 4 per thread
#pragma unroll
        for (int c = 0; c < 4; c++) {
            int ch = tid + c * 256;
            int r  = ch >> 3;            // 0..127
            int c8 = (ch & 7) << 3;      // 0,8,...,56
            int ra = GATHER ? row_idx[m0 + r] : (m0 + r);
            if (AF32) {
                const float* Af = (const float*)Ap + (size_t)ra * K + kt + c8;
                f32x4 v0 = *(const f32x4*)Af;
                f32x4 v1 = *(const f32x4*)(Af + 4);
                u16x8 o;
                o[0]=f2bf(v0[0]); o[1]=f2bf(v0[1]); o[2]=f2bf(v0[2]); o[3]=f2bf(v0[3]);
                o[4]=f2bf(v1[0]); o[5]=f2bf(v1[1]); o[6]=f2bf(v1[2]); o[7]=f2bf(v1[3]);
                *(u16x8*)&As[r][c8] = o;
            } else {
                const unsigned short* Au =
                    (const unsigned short*)Ap + (size_t)ra * K + kt + c8;
                *(u16x8*)&As[r][c8] = *(const u16x8*)Au;
            }
        }
        // --- stage B transposed: global fp32 [BK][128] -> bf16 LDS Bs[n][k]
#pragma unroll
        for (int c = 0; c < 4; c++) {
            int ch = tid + c * 256;
            int kk = ch >> 4;            // 0..63
            int c8 = (ch & 15) << 3;     // 0,8,...,120 (local n)
            const float* Bf = Bp + (size_t)(kt + kk) * N + n0 + c8;
            f32x4 v0 = *(const f32x4*)Bf;
            f32x4 v1 = *(const f32x4*)(Bf + 4);
            Bs[c8 + 0][kk] = f2bf(v0[0]);
            Bs[c8 + 1][kk] = f2bf(v0[1]);
            Bs[c8 + 2][kk] = f2bf(v0[2]);
            Bs[c8 + 3][kk] = f2bf(v0[3]);
            Bs[c8 + 4][kk] = f2bf(v1[0]);
            Bs[c8 + 5][kk] = f2bf(v1[1]);
            Bs[c8 + 6][kk] = f2bf(v1[2]);
            Bs[c8 + 7][kk] = f2bf(v1[3]);
        }
        __syncthreads();

#pragma unroll
        for (int ks = 0; ks < BK; ks += 32) {
            bf16x8 af[4], bfr[4];
#pragma unroll
            for (int mt = 0; mt < 4; mt++)
                af[mt] = __builtin_bit_cast(bf16x8,
                    *(const u16x8*)&As[wm + mt * 16 + lrow][ks + quad * 8]);
#pragma unroll
            for (int nt = 0; nt < 4; nt++)
                bfr[nt] = __builtin_bit_cast(bf16x8,
                    *(const u16x8*)&Bs[wn + nt * 16 + lrow][ks + quad * 8]);
#pragma unroll
            for (int mt = 0; mt < 4; mt++)
#pragma unroll
                for (int nt = 0; nt < 4; nt++)
                    acc[mt][nt] = __builtin_amdgcn_mfma_f32_16x16x32_bf16(
                        af[mt], bfr[nt], acc[mt][nt], 0, 0, 0);
        }
        __syncthreads();
    }

    // epilogue: D row = quad*4 + r, col = lane&15  (HW-verified C/D layout)
#pragma unroll
    for (int mt = 0; mt < 4; mt++)
#pragma unroll
        for (int nt = 0; nt < 4; nt++)
#pragma unroll
            for (int r = 0; r < 4; r++) {
                int row = m0 + wm + mt * 16 + quad * 4 + r;
                int col = n0 + wn + nt * 16 + lrow;
                if (OUTF32)
                    ((float*)Cp)[(size_t)row * N + col] = acc[mt][nt][r];
                else
                    ((__hip_bfloat16*)Cp)[(size_t)row * N + col] =
                        __float2bfloat16(acc[mt][nt][r]);
            }
}

// ---------------------------------------------------------------------------
// RoPE-style mix (in place on bf16 qkv, windowed order):
//   q' = q*cos[wi[s]] + k*sin[wi[s]];  k' = k*cos[wi[s]] - q*sin[wi[s]]
// cos/sin are fp32 inputs. Grid exactly covers S*C.
// ---------------------------------------------------------------------------
__global__ void rope_kernel(__hip_bfloat16* __restrict__ qkv,
                            const float* __restrict__ cosp,
                            const float* __restrict__ sinp,
                            const int* __restrict__ wi)
{
    int idx = blockIdx.x * blockDim.x + threadIdx.x;   // over S*C (exact)
    int s = idx / C_DIM;
    int c = idx - s * C_DIM;
    int d = c % D_DIM;
    int src = wi[s];
    float cw = cosp[src * D_DIM + d];
    float sw = sinp[src * D_DIM + d];
    size_t base = (size_t)s * C3_DIM;
    float q = __bfloat162float(qkv[base + c]);
    float k = __bfloat162float(qkv[base + C_DIM + c]);
    qkv[base + c]         = __float2bfloat16(q * cw + k * sw);
    qkv[base + C_DIM + c] = __float2bfloat16(k * cw - q * sw);
}

// ---------------------------------------------------------------------------
// Block attention: one workgroup per (block b, head h).
// 16x16 scores over D=80, row softmax, 16x80 PV, fp32 in LDS.
// Output row j written directly to un-permuted position wi[j]
// (y_final[p[j]] = y_w[j], since argsort(p) = p^-1).
// ---------------------------------------------------------------------------
__global__ __launch_bounds__(256) void attn_kernel(
    const __hip_bfloat16* __restrict__ qkv,
    __hip_bfloat16* __restrict__ y,
    const int* __restrict__ wi)
{
    const int b = blockIdx.x;
    const int h = blockIdx.y;
    __shared__ float qs[BLK][D_DIM], ks[BLK][D_DIM], vs[BLK][D_DIM];
    __shared__ float pr[BLK][BLK];
    __shared__ int   orow[BLK];
    const int tid = threadIdx.x;

    if (tid < BLK) orow[tid] = wi[b * BLK + tid];
    for (int i = tid; i < BLK * D_DIM; i += 256) {
        int r = i / D_DIM, d = i - r * D_DIM;
        size_t base = (size_t)(b * BLK + r) * C3_DIM + h * D_DIM + d;
        qs[r][d] = __bfloat162float(qkv[base]);
        ks[r][d] = __bfloat162float(qkv[base + C_DIM]);
        vs[r][d] = __bfloat162float(qkv[base + 2 * C_DIM]);
    }
    __syncthreads();
    {
        int i = tid >> 4, j = tid & 15;
        float a = 0.f;
#pragma unroll
        for (int d = 0; d < D_DIM; d++) a += qs[i][d] * ks[j][d];
        pr[i][j] = a * 0.11180339887498948f;   // 1/sqrt(80)
    }
    __syncthreads();
    if (tid < BLK) {
        float m = -1e30f;
#pragma unroll
        for (int j = 0; j < BLK; j++) m = fmaxf(m, pr[tid][j]);
        float sum = 0.f;
        float e[BLK];
#pragma unroll
        for (int j = 0; j < BLK; j++) { e[j] = __expf(pr[tid][j] - m); sum += e[j]; }
        float inv = 1.f / sum;
#pragma unroll
        for (int j = 0; j < BLK; j++) pr[tid][j] = e[j] * inv;
    }
    __syncthreads();
    for (int i = tid; i < BLK * D_DIM; i += 256) {
        int r = i / D_DIM, d = i - r * D_DIM;
        float a = 0.f;
#pragma unroll
        for (int j = 0; j < BLK; j++) a += pr[r][j] * vs[j][d];
        y[(size_t)orow[r] * C_DIM + h * D_DIM + d] = __float2bfloat16(a);
    }
}

extern "C" void kernel_launch(void* const* d_in, const int* in_sizes, int n_in,
                              void* d_out, int out_size, void* d_ws, size_t ws_size,
                              hipStream_t stream)
{
    const float* x     = (const float*)d_in[0];
    const float* cosp  = (const float*)d_in[1];
    const float* sinp  = (const float*)d_in[2];
    const float* Wqkv  = (const float*)d_in[3];
    const float* Wproj = (const float*)d_in[4];
    const int*   wi    = (const int*)d_in[5];

    // workspace: qkv (S*3840 bf16) + y (S*1280 bf16) = exactly 160 MiB.
    char* ws = (char*)d_ws;
    __hip_bfloat16* qkv = (__hip_bfloat16*)ws;
    __hip_bfloat16* yun = (__hip_bfloat16*)(ws + (size_t)S_TOK * C3_DIM * 2);

    // 1) qkv = bf16(x[wi]) @ bf16(W_qkv)   (convert fused into staging; bf16 out)
    gemm_mfma<true, true, false><<<dim3(S_TOK / TM, C3_DIM / TN), 256, 0, stream>>>(
        x, Wqkv, qkv, wi, C3_DIM, C_DIM);

    // 2) rope mix in place (windowed order); S*C/256 = 81920 blocks exact
    rope_kernel<<<S_TOK * C_DIM / 256, 256, 0, stream>>>(qkv, cosp, sinp, wi);

    // 3) block attention; scatter rows to un-permuted order (bf16 workspace)
    attn_kernel<<<dim3(S_TOK / BLK, H_DIM), 256, 0, stream>>>(qkv, yun, wi);

    // 4) out = y @ bf16(W_proj)  -> FP32 output (reference output dtype)
    gemm_mfma<false, false, true><<<dim3(S_TOK / TM, C_DIM / TN), 256, 0, stream>>>(
        yun, Wproj, d_out, nullptr, C_DIM, C_DIM);
}

// Round 6
// 649.890 us; speedup vs baseline: 1.9887x; 1.9887x over previous
//
#include <hip/hip_runtime.h>
#include <hip/hip_bf16.h>

// Problem constants (fixed by setup_inputs):
//   B=1, T=16384 -> S=16384, C=1280, H=16, D=80, 3C=3840, block=16, nb=1024
// Inputs FP32, output FP32 (established R5). Workspace >= 223 MB (proven by
// R2/R3 bit-identity with R2 buffers at 222.8 MB).
#define S_TOK   16384
#define C_DIM   1280
#define C3_DIM  3840
#define H_DIM   16
#define D_DIM   80
#define BLK     16

using u16x8  = __attribute__((ext_vector_type(8))) unsigned short;
using bf16x8 = __attribute__((ext_vector_type(8))) __bf16;
using f32x4  = __attribute__((ext_vector_type(4))) float;

__device__ __forceinline__ unsigned short f2bf(float f) {
    return __bfloat16_as_ushort(__float2bfloat16(f));
}

// ---------------------------------------------------------------------------
// One-shot weight prep: fp32 W[K][N] -> bf16 W^T[N][K], LDS-tiled.
// Moves the transpose OUT of the GEMM hot loop (R5: 3.15e8 LDS bank-conflict
// cycles = 66% of GEMM1 came from transpose-on-write).
// ---------------------------------------------------------------------------
__global__ __launch_bounds__(256) void transpose_cvt(
    const float* __restrict__ W, unsigned short* __restrict__ WT, int K, int N)
{
    __shared__ float tile[32][33];
    const int n0 = blockIdx.x * 32, k0 = blockIdx.y * 32;
    const int tx = threadIdx.x & 31, ty = threadIdx.x >> 5;   // 32x8
#pragma unroll
    for (int i = ty; i < 32; i += 8)
        tile[i][tx] = W[(size_t)(k0 + i) * N + n0 + tx];
    __syncthreads();
#pragma unroll
    for (int i = ty; i < 32; i += 8)
        WT[(size_t)(n0 + i) * K + k0 + tx] = f2bf(tile[tx][i]);
}

// ---------------------------------------------------------------------------
// Tiled bf16 MFMA GEMM.
//   A: [M][K] fp32 (AF32, converted in staging) or bf16; optional row gather.
//   B: bf16 [N][K] (PRE-TRANSPOSED) -> staging is a conflict-free row copy.
//   C[m][n] = sum_k A[g(m)][k] * BT[n][k];  out fp32 (OUTF32) or bf16.
// 128x128 tile, BK=64, 4 waves (2x2), each wave 64x64 via 4x4 16x16x32 MFMAs.
// ---------------------------------------------------------------------------
#define TM 128
#define TN 128
#define BK 64
#define LDST 72   // BK + 8 pad; row stride 144 B keeps 16B alignment

template<bool AF32, bool GATHER, bool OUTF32>
__global__ __launch_bounds__(256) void gemm_mfma(
    const void* __restrict__ Ap,            // [M][K] fp32 or bf16
    const unsigned short* __restrict__ BT,  // [N][K] bf16
    void* __restrict__ Cp,                  // [M][N] fp32 or bf16
    const int* __restrict__ row_idx,        // used iff GATHER
    int N, int K)
{
    __shared__ __align__(16) unsigned short As[TM][LDST];
    __shared__ __align__(16) unsigned short Bs[TN][LDST];  // Bs[n][k]

    const int m0   = blockIdx.x * TM;
    const int n0   = blockIdx.y * TN;
    const int tid  = threadIdx.x;
    const int lane = tid & 63;
    const int wave = tid >> 6;
    const int wm   = (wave >> 1) * 64;
    const int wn   = (wave & 1) * 64;
    const int lrow = lane & 15;
    const int quad = lane >> 4;

    f32x4 acc[4][4];
#pragma unroll
    for (int i = 0; i < 4; i++)
#pragma unroll
        for (int j = 0; j < 4; j++)
            acc[i][j] = (f32x4){0.f, 0.f, 0.f, 0.f};

    for (int kt = 0; kt < K; kt += BK) {
        // --- stage A: 128 rows x 64 k, 1024 chunks of 8, 4 per thread
#pragma unroll
        for (int c = 0; c < 4; c++) {
            int ch = tid + c * 256;
            int r  = ch >> 3;            // 0..127
            int c8 = (ch & 7) << 3;      // 0..56
            int ra = GATHER ? row_idx[m0 + r] : (m0 + r);
            if (AF32) {
                const float* Af = (const float*)Ap + (size_t)ra * K + kt + c8;
                f32x4 v0 = *(const f32x4*)Af;
                f32x4 v1 = *(const f32x4*)(Af + 4);
                u16x8 o;
                o[0]=f2bf(v0[0]); o[1]=f2bf(v0[1]); o[2]=f2bf(v0[2]); o[3]=f2bf(v0[3]);
                o[4]=f2bf(v1[0]); o[5]=f2bf(v1[1]); o[6]=f2bf(v1[2]); o[7]=f2bf(v1[3]);
                *(u16x8*)&As[r][c8] = o;
            } else {
                const unsigned short* Au =
                    (const unsigned short*)Ap + (size_t)ra * K + kt + c8;
                *(u16x8*)&As[r][c8] = *(const u16x8*)Au;
            }
        }
        // --- stage B: straight row copy from pre-transposed bf16 BT
#pragma unroll
        for (int c = 0; c < 4; c++) {
            int ch = tid + c * 256;
            int n  = ch >> 3;            // 0..127
            int c8 = (ch & 7) << 3;      // 0..56
            *(u16x8*)&Bs[n][c8] =
                *(const u16x8*)(BT + (size_t)(n0 + n) * K + kt + c8);
        }
        __syncthreads();

#pragma unroll
        for (int ks = 0; ks < BK; ks += 32) {
            bf16x8 af[4], bfr[4];
#pragma unroll
            for (int mt = 0; mt < 4; mt++)
                af[mt] = __builtin_bit_cast(bf16x8,
                    *(const u16x8*)&As[wm + mt * 16 + lrow][ks + quad * 8]);
#pragma unroll
            for (int nt = 0; nt < 4; nt++)
                bfr[nt] = __builtin_bit_cast(bf16x8,
                    *(const u16x8*)&Bs[wn + nt * 16 + lrow][ks + quad * 8]);
#pragma unroll
            for (int mt = 0; mt < 4; mt++)
#pragma unroll
                for (int nt = 0; nt < 4; nt++)
                    acc[mt][nt] = __builtin_amdgcn_mfma_f32_16x16x32_bf16(
                        af[mt], bfr[nt], acc[mt][nt], 0, 0, 0);
        }
        __syncthreads();
    }

    // epilogue: D row = quad*4 + r, col = lane&15  (HW-verified C/D layout)
#pragma unroll
    for (int mt = 0; mt < 4; mt++)
#pragma unroll
        for (int nt = 0; nt < 4; nt++)
#pragma unroll
            for (int r = 0; r < 4; r++) {
                int row = m0 + wm + mt * 16 + quad * 4 + r;
                int col = n0 + wn + nt * 16 + lrow;
                if (OUTF32)
                    ((float*)Cp)[(size_t)row * N + col] = acc[mt][nt][r];
                else
                    ((__hip_bfloat16*)Cp)[(size_t)row * N + col] =
                        __float2bfloat16(acc[mt][nt][r]);
            }
}

// ---------------------------------------------------------------------------
// RoPE-style mix (in place on bf16 qkv, windowed order):
//   q' = q*cos[wi[s]] + k*sin[wi[s]];  k' = k*cos[wi[s]] - q*sin[wi[s]]
// ---------------------------------------------------------------------------
__global__ void rope_kernel(__hip_bfloat16* __restrict__ qkv,
                            const float* __restrict__ cosp,
                            const float* __restrict__ sinp,
                            const int* __restrict__ wi)
{
    int idx = blockIdx.x * blockDim.x + threadIdx.x;   // over S*C (exact)
    int s = idx / C_DIM;
    int c = idx - s * C_DIM;
    int d = c % D_DIM;
    int src = wi[s];
    float cw = cosp[src * D_DIM + d];
    float sw = sinp[src * D_DIM + d];
    size_t base = (size_t)s * C3_DIM;
    float q = __bfloat162float(qkv[base + c]);
    float k = __bfloat162float(qkv[base + C_DIM + c]);
    qkv[base + c]         = __float2bfloat16(q * cw + k * sw);
    qkv[base + C_DIM + c] = __float2bfloat16(k * cw - q * sw);
}

// ---------------------------------------------------------------------------
// Block attention: one workgroup per (block b, head h).
// 16x16 scores over D=80, row softmax, 16x80 PV, fp32 in LDS.
// Row j scattered to un-permuted position wi[j] (argsort(p) = p^-1).
// ---------------------------------------------------------------------------
__global__ __launch_bounds__(256) void attn_kernel(
    const __hip_bfloat16* __restrict__ qkv,
    __hip_bfloat16* __restrict__ y,
    const int* __restrict__ wi)
{
    const int b = blockIdx.x;
    const int h = blockIdx.y;
    __shared__ float qs[BLK][D_DIM], ks[BLK][D_DIM], vs[BLK][D_DIM];
    __shared__ float pr[BLK][BLK];
    __shared__ int   orow[BLK];
    const int tid = threadIdx.x;

    if (tid < BLK) orow[tid] = wi[b * BLK + tid];
    for (int i = tid; i < BLK * D_DIM; i += 256) {
        int r = i / D_DIM, d = i - r * D_DIM;
        size_t base = (size_t)(b * BLK + r) * C3_DIM + h * D_DIM + d;
        qs[r][d] = __bfloat162float(qkv[base]);
        ks[r][d] = __bfloat162float(qkv[base + C_DIM]);
        vs[r][d] = __bfloat162float(qkv[base + 2 * C_DIM]);
    }
    __syncthreads();
    {
        int i = tid >> 4, j = tid & 15;
        float a = 0.f;
#pragma unroll
        for (int d = 0; d < D_DIM; d++) a += qs[i][d] * ks[j][d];
        pr[i][j] = a * 0.11180339887498948f;   // 1/sqrt(80)
    }
    __syncthreads();
    if (tid < BLK) {
        float m = -1e30f;
#pragma unroll
        for (int j = 0; j < BLK; j++) m = fmaxf(m, pr[tid][j]);
        float sum = 0.f;
        float e[BLK];
#pragma unroll
        for (int j = 0; j < BLK; j++) { e[j] = __expf(pr[tid][j] - m); sum += e[j]; }
        float inv = 1.f / sum;
#pragma unroll
        for (int j = 0; j < BLK; j++) pr[tid][j] = e[j] * inv;
    }
    __syncthreads();
    for (int i = tid; i < BLK * D_DIM; i += 256) {
        int r = i / D_DIM, d = i - r * D_DIM;
        float a = 0.f;
#pragma unroll
        for (int j = 0; j < BLK; j++) a += pr[r][j] * vs[j][d];
        y[(size_t)orow[r] * C_DIM + h * D_DIM + d] = __float2bfloat16(a);
    }
}

extern "C" void kernel_launch(void* const* d_in, const int* in_sizes, int n_in,
                              void* d_out, int out_size, void* d_ws, size_t ws_size,
                              hipStream_t stream)
{
    const float* x     = (const float*)d_in[0];
    const float* cosp  = (const float*)d_in[1];
    const float* sinp  = (const float*)d_in[2];
    const float* Wqkv  = (const float*)d_in[3];
    const float* Wproj = (const float*)d_in[4];
    const int*   wi    = (const int*)d_in[5];

    // workspace layout (bytes):
    //   qkv    @ 0          : S*3840*2 = 125,829,120
    //   yun    @ 125829120  : S*1280*2 =  41,943,040
    //   wqkvT  @ 167772160  : 3840*1280*2 = 9,830,400   (bf16 [N][K])
    //   wprojT @ 177602560  : 1280*1280*2 = 3,276,800   (bf16 [N][K])
    // total 180,879,360 < 223 MB proven available.
    char* ws = (char*)d_ws;
    __hip_bfloat16* qkv    = (__hip_bfloat16*)ws;
    __hip_bfloat16* yun    = (__hip_bfloat16*)(ws + 125829120ull);
    unsigned short* wqkvT  = (unsigned short*)(ws + 167772160ull);
    unsigned short* wprojT = (unsigned short*)(ws + 177602560ull);

    // 0) weight prep: fp32 [K][N] -> bf16 [N][K]
    transpose_cvt<<<dim3(C3_DIM / 32, C_DIM / 32), 256, 0, stream>>>(
        Wqkv, wqkvT, C_DIM, C3_DIM);
    transpose_cvt<<<dim3(C_DIM / 32, C_DIM / 32), 256, 0, stream>>>(
        Wproj, wprojT, C_DIM, C_DIM);

    // 1) qkv = bf16(x[wi]) @ W_qkv   (bf16 out to workspace)
    gemm_mfma<true, true, false><<<dim3(S_TOK / TM, C3_DIM / TN), 256, 0, stream>>>(
        x, wqkvT, qkv, wi, C3_DIM, C_DIM);

    // 2) rope mix in place (windowed order); S*C/256 blocks exact
    rope_kernel<<<S_TOK * C_DIM / 256, 256, 0, stream>>>(qkv, cosp, sinp, wi);

    // 3) block attention; scatter rows to un-permuted order
    attn_kernel<<<dim3(S_TOK / BLK, H_DIM), 256, 0, stream>>>(qkv, yun, wi);

    // 4) out = y @ W_proj -> fp32 d_out
    gemm_mfma<false, false, true><<<dim3(S_TOK / TM, C_DIM / TN), 256, 0, stream>>>(
        yun, wprojT, d_out, nullptr, C_DIM, C_DIM);
}